// Round 1
// baseline (202.747 us; speedup 1.0000x reference)
//
#include <hip/hip_runtime.h>

// SSIM, fused separable 11x11 Gaussian blur + ssim map + mean.
// Images: (16,3,512,512) f32. Output: 1 f32 scalar.

#define TW 64            // tile width (output cols per block)
#define TH 32            // tile height (output rows per block)
#define RH (TH + 10)     // rows of horizontally-blurred data needed (42)
#define IMGW 512
#define IMGH 512
#define NPL 48           // 16*3 planes
#define NTX (IMGW / TW)  // 8
#define NTY (IMGH / TH)  // 16
#define NBLOCKS (NPL * NTX * NTY)  // 6144
#define NPIX 12582912.0  // 16*3*512*512

__device__ __forceinline__ float4 f4fma(float a, const float4 b, const float4 c) {
    return make_float4(fmaf(a, b.x, c.x), fmaf(a, b.y, c.y),
                       fmaf(a, b.z, c.z), fmaf(a, b.w, c.w));
}

__device__ __forceinline__ float ssim1(float mu1, float mu2, float exx, float eyy, float exy) {
    const float C1 = 1.0e-4f;   // 0.01^2
    const float C2 = 9.0e-4f;   // 0.03^2
    float mu1s = mu1 * mu1;
    float mu2s = mu2 * mu2;
    float mu12 = mu1 * mu2;
    float s1  = exx - mu1s;
    float s2  = eyy - mu2s;
    float s12 = exy - mu12;
    float num = (2.0f * mu12 + C1) * (2.0f * s12 + C2);
    float den = (mu1s + mu2s + C1) * (s1 + s2 + C2);
    return num / den;
}

__global__ __launch_bounds__(256, 3) void ssim_main(const float* __restrict__ img1,
                                                    const float* __restrict__ img2,
                                                    float* __restrict__ partial) {
    // 11-tap gaussian, sigma=1.5, normalized (double-precision precomputed)
    constexpr float G[11] = {0.00102838f, 0.00759876f, 0.03600077f, 0.10936069f,
                             0.21300554f, 0.26601172f, 0.21300554f, 0.10936069f,
                             0.03600077f, 0.00759876f, 0.00102838f};

    __shared__ __align__(16) float sHX [RH][TW];
    __shared__ __align__(16) float sHY [RH][TW];
    __shared__ __align__(16) float sHXX[RH][TW];
    __shared__ __align__(16) float sHYY[RH][TW];
    __shared__ __align__(16) float sHXY[RH][TW];

    const int bid   = blockIdx.x;
    const int plane = bid / (NTX * NTY);
    const int rem   = bid % (NTX * NTY);
    const int tyi   = rem / NTX;
    const int txi   = rem % NTX;
    const int row0  = tyi * TH;
    const int col0  = txi * TW;
    const float* __restrict__ p1 = img1 + (size_t)plane * (IMGH * IMGW);
    const float* __restrict__ p2 = img2 + (size_t)plane * (IMGH * IMGW);
    const int tid = threadIdx.x;

    // ---------- stage 1: horizontal blur of 5 quantities, 4 cols per task ----------
    // tasks: RH rows x 16 col-groups = 672
    for (int idx = tid; idx < RH * (TW / 4); idx += 256) {
        const int r  = idx >> 4;          // 0..41
        const int c0 = (idx & 15) << 2;   // 0..60
        const int gr = row0 + r - 5;
        float sx[4]  = {0, 0, 0, 0};
        float sy[4]  = {0, 0, 0, 0};
        float sxx[4] = {0, 0, 0, 0};
        float syy[4] = {0, 0, 0, 0};
        float sxy[4] = {0, 0, 0, 0};
        if (gr >= 0 && gr < IMGH) {
            const float* __restrict__ r1 = p1 + gr * IMGW;
            const float* __restrict__ r2 = p2 + gr * IMGW;
            const int gb = col0 + c0 - 5;
            float xv[14], yv[14], xx[14], yy[14], xy[14];
            #pragma unroll
            for (int k = 0; k < 14; ++k) {
                const int gc = gb + k;
                const bool ok = ((unsigned)gc < (unsigned)IMGW);
                xv[k] = ok ? r1[gc] : 0.0f;
                yv[k] = ok ? r2[gc] : 0.0f;
            }
            #pragma unroll
            for (int k = 0; k < 14; ++k) {
                xx[k] = xv[k] * xv[k];
                yy[k] = yv[k] * yv[k];
                xy[k] = xv[k] * yv[k];
            }
            #pragma unroll
            for (int j = 0; j < 4; ++j) {
                #pragma unroll
                for (int k = 0; k < 11; ++k) {
                    const float w = G[k];
                    sx[j]  = fmaf(w, xv[j + k], sx[j]);
                    sy[j]  = fmaf(w, yv[j + k], sy[j]);
                    sxx[j] = fmaf(w, xx[j + k], sxx[j]);
                    syy[j] = fmaf(w, yy[j + k], syy[j]);
                    sxy[j] = fmaf(w, xy[j + k], sxy[j]);
                }
            }
        }
        *(float4*)&sHX [r][c0] = make_float4(sx[0],  sx[1],  sx[2],  sx[3]);
        *(float4*)&sHY [r][c0] = make_float4(sy[0],  sy[1],  sy[2],  sy[3]);
        *(float4*)&sHXX[r][c0] = make_float4(sxx[0], sxx[1], sxx[2], sxx[3]);
        *(float4*)&sHYY[r][c0] = make_float4(syy[0], syy[1], syy[2], syy[3]);
        *(float4*)&sHXY[r][c0] = make_float4(sxy[0], sxy[1], sxy[2], sxy[3]);
    }
    __syncthreads();

    // ---------- stage 2: vertical blur (4x4 register block) + ssim + accumulate ----------
    float acc = 0.0f;
    if (tid < 128) {
        const int r0 = (tid >> 4) << 2;   // 0,4,...,28
        const int c0 = (tid & 15) << 2;   // 0..60
        float4 ax[4], ay[4], axx[4], ayy[4], axy[4];
        #pragma unroll
        for (int j = 0; j < 4; ++j) {
            ax[j] = make_float4(0, 0, 0, 0);
            ay[j] = ax[j]; axx[j] = ax[j]; ayy[j] = ax[j]; axy[j] = ax[j];
        }
        #pragma unroll
        for (int rr = 0; rr < 14; ++rr) {
            const float4 vx  = *(const float4*)&sHX [r0 + rr][c0];
            const float4 vy  = *(const float4*)&sHY [r0 + rr][c0];
            const float4 vxx = *(const float4*)&sHXX[r0 + rr][c0];
            const float4 vyy = *(const float4*)&sHYY[r0 + rr][c0];
            const float4 vxy = *(const float4*)&sHXY[r0 + rr][c0];
            #pragma unroll
            for (int j = 0; j < 4; ++j) {
                const int k = rr - j;
                if (k >= 0 && k < 11) {
                    const float w = G[k];
                    ax[j]  = f4fma(w, vx,  ax[j]);
                    ay[j]  = f4fma(w, vy,  ay[j]);
                    axx[j] = f4fma(w, vxx, axx[j]);
                    ayy[j] = f4fma(w, vyy, ayy[j]);
                    axy[j] = f4fma(w, vxy, axy[j]);
                }
            }
        }
        #pragma unroll
        for (int j = 0; j < 4; ++j) {
            acc += ssim1(ax[j].x, ay[j].x, axx[j].x, ayy[j].x, axy[j].x);
            acc += ssim1(ax[j].y, ay[j].y, axx[j].y, ayy[j].y, axy[j].y);
            acc += ssim1(ax[j].z, ay[j].z, axx[j].z, ayy[j].z, axy[j].z);
            acc += ssim1(ax[j].w, ay[j].w, axx[j].w, ayy[j].w, axy[j].w);
        }
    }

    // ---------- block reduction ----------
    #pragma unroll
    for (int off = 32; off > 0; off >>= 1)
        acc += __shfl_down(acc, off, 64);
    __shared__ float wsum[4];
    if ((tid & 63) == 0) wsum[tid >> 6] = acc;
    __syncthreads();
    if (tid == 0)
        partial[bid] = wsum[0] + wsum[1] + wsum[2] + wsum[3];
}

__global__ __launch_bounds__(256) void ssim_reduce(const float* __restrict__ partial,
                                                   float* __restrict__ out) {
    const int tid = threadIdx.x;
    double s = 0.0;
    for (int i = tid; i < NBLOCKS; i += 256)
        s += (double)partial[i];
    #pragma unroll
    for (int off = 32; off > 0; off >>= 1)
        s += __shfl_down(s, off, 64);
    __shared__ double wsd[4];
    if ((tid & 63) == 0) wsd[tid >> 6] = s;
    __syncthreads();
    if (tid == 0)
        out[0] = (float)((wsd[0] + wsd[1] + wsd[2] + wsd[3]) / NPIX);
}

extern "C" void kernel_launch(void* const* d_in, const int* in_sizes, int n_in,
                              void* d_out, int out_size, void* d_ws, size_t ws_size,
                              hipStream_t stream) {
    const float* img1 = (const float*)d_in[0];
    const float* img2 = (const float*)d_in[1];
    float* partial = (float*)d_ws;      // 6144 floats = 24 KB of scratch
    float* out = (float*)d_out;
    ssim_main<<<NBLOCKS, 256, 0, stream>>>(img1, img2, partial);
    ssim_reduce<<<1, 256, 0, stream>>>(partial, out);
}

// Round 2
// 143.050 us; speedup vs baseline: 1.4173x; 1.4173x over previous
//
#include <hip/hip_runtime.h>

// SSIM, fused separable 11x11 Gaussian blur + ssim map + mean.
// Images: (16,3,512,512) f32. Output: 1 f32 scalar.
// R2: spill-free stage 1 (stream-scatter, no product arrays), full-256-thread
// stage 2 (2 rows x 4 cols per thread).

#define TW 64            // tile width (output cols per block)
#define TH 32            // tile height (output rows per block)
#define RH (TH + 10)     // rows of horizontally-blurred data needed (42)
#define IMGW 512
#define IMGH 512
#define NPL 48           // 16*3 planes
#define NTX (IMGW / TW)  // 8
#define NTY (IMGH / TH)  // 16
#define NBLOCKS (NPL * NTX * NTY)  // 6144
#define NPIX 12582912.0  // 16*3*512*512

__device__ __forceinline__ float4 f4fma(float a, const float4 b, const float4 c) {
    return make_float4(fmaf(a, b.x, c.x), fmaf(a, b.y, c.y),
                       fmaf(a, b.z, c.z), fmaf(a, b.w, c.w));
}

__device__ __forceinline__ float ssim1(float mu1, float mu2, float exx, float eyy, float exy) {
    const float C1 = 1.0e-4f;   // 0.01^2
    const float C2 = 9.0e-4f;   // 0.03^2
    float mu1s = mu1 * mu1;
    float mu2s = mu2 * mu2;
    float mu12 = mu1 * mu2;
    float s1  = exx - mu1s;
    float s2  = eyy - mu2s;
    float s12 = exy - mu12;
    float num = (2.0f * mu12 + C1) * (2.0f * s12 + C2);
    float den = (mu1s + mu2s + C1) * (s1 + s2 + C2);
    return num / den;
}

__global__ __launch_bounds__(256, 3) void ssim_main(const float* __restrict__ img1,
                                                    const float* __restrict__ img2,
                                                    float* __restrict__ partial) {
    // 11-tap gaussian, sigma=1.5, normalized (double-precision precomputed)
    constexpr float G[11] = {0.00102838f, 0.00759876f, 0.03600077f, 0.10936069f,
                             0.21300554f, 0.26601172f, 0.21300554f, 0.10936069f,
                             0.03600077f, 0.00759876f, 0.00102838f};

    __shared__ __align__(16) float sHX [RH][TW];
    __shared__ __align__(16) float sHY [RH][TW];
    __shared__ __align__(16) float sHXX[RH][TW];
    __shared__ __align__(16) float sHYY[RH][TW];
    __shared__ __align__(16) float sHXY[RH][TW];

    const int bid   = blockIdx.x;
    const int plane = bid / (NTX * NTY);
    const int rem   = bid % (NTX * NTY);
    const int tyi   = rem / NTX;
    const int txi   = rem % NTX;
    const int row0  = tyi * TH;
    const int col0  = txi * TW;
    const float* __restrict__ p1 = img1 + (size_t)plane * (IMGH * IMGW);
    const float* __restrict__ p2 = img2 + (size_t)plane * (IMGH * IMGW);
    const int tid = threadIdx.x;

    // ---------- stage 1: horizontal blur of 5 quantities, 4 cols per task ----------
    // tasks: RH rows x 16 col-groups = 672.  No product arrays: compute
    // a,b,a^2,b^2,ab per window column and scatter-FMA into 20 accumulators.
    for (int idx = tid; idx < RH * (TW / 4); idx += 256) {
        const int r  = idx >> 4;          // 0..41
        const int c0 = (idx & 15) << 2;   // 0..60
        const int gr = row0 + r - 5;
        float sx[4]  = {0, 0, 0, 0};
        float sy[4]  = {0, 0, 0, 0};
        float sxx[4] = {0, 0, 0, 0};
        float syy[4] = {0, 0, 0, 0};
        float sxy[4] = {0, 0, 0, 0};
        if (gr >= 0 && gr < IMGH) {
            const float* __restrict__ r1 = p1 + gr * IMGW;
            const float* __restrict__ r2 = p2 + gr * IMGW;
            const int gb = col0 + c0 - 5;
            float xv[14], yv[14];
            #pragma unroll
            for (int k = 0; k < 14; ++k) {
                const int gc = gb + k;
                const bool ok = ((unsigned)gc < (unsigned)IMGW);
                xv[k] = ok ? r1[gc] : 0.0f;
                yv[k] = ok ? r2[gc] : 0.0f;
            }
            #pragma unroll
            for (int k = 0; k < 14; ++k) {
                const float a = xv[k];
                const float b = yv[k];
                const float pxx = a * a;
                const float pyy = b * b;
                const float pxy = a * b;
                #pragma unroll
                for (int j = 0; j < 4; ++j) {
                    const int t = k - j;
                    if (t >= 0 && t < 11) {
                        const float w = G[t];
                        sx[j]  = fmaf(w, a,   sx[j]);
                        sy[j]  = fmaf(w, b,   sy[j]);
                        sxx[j] = fmaf(w, pxx, sxx[j]);
                        syy[j] = fmaf(w, pyy, syy[j]);
                        sxy[j] = fmaf(w, pxy, sxy[j]);
                    }
                }
            }
        }
        *(float4*)&sHX [r][c0] = make_float4(sx[0],  sx[1],  sx[2],  sx[3]);
        *(float4*)&sHY [r][c0] = make_float4(sy[0],  sy[1],  sy[2],  sy[3]);
        *(float4*)&sHXX[r][c0] = make_float4(sxx[0], sxx[1], sxx[2], sxx[3]);
        *(float4*)&sHYY[r][c0] = make_float4(syy[0], syy[1], syy[2], syy[3]);
        *(float4*)&sHXY[r][c0] = make_float4(sxy[0], sxy[1], sxy[2], sxy[3]);
    }
    __syncthreads();

    // ---------- stage 2: vertical blur (2 rows x 4 cols per thread) + ssim ----------
    float acc = 0.0f;
    {
        const int r0 = (tid >> 4) << 1;   // 0,2,...,30
        const int c0 = (tid & 15) << 2;   // 0..60
        float4 ax[2], ay[2], axx[2], ayy[2], axy[2];
        #pragma unroll
        for (int j = 0; j < 2; ++j) {
            ax[j] = make_float4(0, 0, 0, 0);
            ay[j] = ax[j]; axx[j] = ax[j]; ayy[j] = ax[j]; axy[j] = ax[j];
        }
        #pragma unroll
        for (int rr = 0; rr < 12; ++rr) {
            const float4 vx  = *(const float4*)&sHX [r0 + rr][c0];
            const float4 vy  = *(const float4*)&sHY [r0 + rr][c0];
            const float4 vxx = *(const float4*)&sHXX[r0 + rr][c0];
            const float4 vyy = *(const float4*)&sHYY[r0 + rr][c0];
            const float4 vxy = *(const float4*)&sHXY[r0 + rr][c0];
            #pragma unroll
            for (int j = 0; j < 2; ++j) {
                const int k = rr - j;
                if (k >= 0 && k < 11) {
                    const float w = G[k];
                    ax[j]  = f4fma(w, vx,  ax[j]);
                    ay[j]  = f4fma(w, vy,  ay[j]);
                    axx[j] = f4fma(w, vxx, axx[j]);
                    ayy[j] = f4fma(w, vyy, ayy[j]);
                    axy[j] = f4fma(w, vxy, axy[j]);
                }
            }
        }
        #pragma unroll
        for (int j = 0; j < 2; ++j) {
            acc += ssim1(ax[j].x, ay[j].x, axx[j].x, ayy[j].x, axy[j].x);
            acc += ssim1(ax[j].y, ay[j].y, axx[j].y, ayy[j].y, axy[j].y);
            acc += ssim1(ax[j].z, ay[j].z, axx[j].z, ayy[j].z, axy[j].z);
            acc += ssim1(ax[j].w, ay[j].w, axx[j].w, ayy[j].w, axy[j].w);
        }
    }

    // ---------- block reduction ----------
    #pragma unroll
    for (int off = 32; off > 0; off >>= 1)
        acc += __shfl_down(acc, off, 64);
    __shared__ float wsum[4];
    if ((tid & 63) == 0) wsum[tid >> 6] = acc;
    __syncthreads();
    if (tid == 0)
        partial[bid] = wsum[0] + wsum[1] + wsum[2] + wsum[3];
}

__global__ __launch_bounds__(256) void ssim_reduce(const float* __restrict__ partial,
                                                   float* __restrict__ out) {
    const int tid = threadIdx.x;
    double s = 0.0;
    for (int i = tid; i < NBLOCKS; i += 256)
        s += (double)partial[i];
    #pragma unroll
    for (int off = 32; off > 0; off >>= 1)
        s += __shfl_down(s, off, 64);
    __shared__ double wsd[4];
    if ((tid & 63) == 0) wsd[tid >> 6] = s;
    __syncthreads();
    if (tid == 0)
        out[0] = (float)((wsd[0] + wsd[1] + wsd[2] + wsd[3]) / NPIX);
}

extern "C" void kernel_launch(void* const* d_in, const int* in_sizes, int n_in,
                              void* d_out, int out_size, void* d_ws, size_t ws_size,
                              hipStream_t stream) {
    const float* img1 = (const float*)d_in[0];
    const float* img2 = (const float*)d_in[1];
    float* partial = (float*)d_ws;      // 6144 floats = 24 KB of scratch
    float* out = (float*)d_out;
    ssim_main<<<NBLOCKS, 256, 0, stream>>>(img1, img2, partial);
    ssim_reduce<<<1, 256, 0, stream>>>(partial, out);
}

// Round 3
// 86.189 us; speedup vs baseline: 2.3524x; 1.6597x over previous
//
#include <hip/hip_runtime.h>

// SSIM, fused separable 11x11 Gaussian blur + ssim map + mean.
// Images: (16,3,512,512) f32. Output: 1 f32 scalar.
// R3: vertical-first separable blur. Stage 1: vertical blur with fully
// coalesced column loads (no horizontal halo needed), scatter-FMA into 20
// accumulators, write 5 quantities to LDS [5][16][80]. Stage 2: horizontal
// blur via aligned float4 LDS reads + ssim + mean. 25.6 KB LDS -> 6 blocks/CU.

#define TW 64            // output cols per block
#define TH 16            // output rows per block
#define LC 80            // LDS cols: image cols [col0-8, col0+71]
#define IMGW 512
#define IMGH 512
#define NPL 48           // 16*3 planes
#define NTX (IMGW / TW)  // 8
#define NTY (IMGH / TH)  // 32
#define NBLOCKS (NPL * NTX * NTY)  // 12288
#define NPIX 12582912.0  // 16*3*512*512

__device__ __forceinline__ float ssim1(float mu1, float mu2, float exx, float eyy, float exy) {
    const float C1 = 1.0e-4f;   // 0.01^2
    const float C2 = 9.0e-4f;   // 0.03^2
    float mu1s = mu1 * mu1;
    float mu2s = mu2 * mu2;
    float mu12 = mu1 * mu2;
    float s1  = exx - mu1s;
    float s2  = eyy - mu2s;
    float s12 = exy - mu12;
    float num = (2.0f * mu12 + C1) * (2.0f * s12 + C2);
    float den = (mu1s + mu2s + C1) * (s1 + s2 + C2);
    return num / den;
}

// Stage 1: vertical blur of {x, y, x^2, y^2, xy} for one (column, 4-row group).
template<bool EDGE>
__device__ __forceinline__ void stage1(const float* __restrict__ p1,
                                       const float* __restrict__ p2,
                                       int r0, int col0, int tid,
                                       float (*sV)[TH][LC], const float* G) {
    #pragma unroll
    for (int it = 0; it < 2; ++it) {
        const int idx = tid + it * 256;
        if (it == 1 && idx >= LC * (TH / 4)) break;   // 320 tasks total
        const int cl = idx % LC;          // LDS col 0..79
        const int g  = idx / LC;          // 4-row group 0..3
        const int gc = col0 - 8 + cl;     // image col
        float s[5][4] = {};               // [quantity][row-in-group]
        if ((unsigned)gc < (unsigned)IMGW) {
            const float* __restrict__ c1 = p1 + gc;
            const float* __restrict__ c2 = p2 + gc;
            const int rbase = r0 + 4 * g - 5;
            #pragma unroll
            for (int k = 0; k < 14; ++k) {
                const int row = rbase + k;
                float a, b;
                if (EDGE) {
                    const bool ok = ((unsigned)row < (unsigned)IMGH);
                    const int rc = ok ? row : 0;
                    a = c1[(size_t)rc * IMGW];
                    b = c2[(size_t)rc * IMGW];
                    a = ok ? a : 0.0f;
                    b = ok ? b : 0.0f;
                } else {
                    a = c1[(size_t)row * IMGW];
                    b = c2[(size_t)row * IMGW];
                }
                const float pxx = a * a;
                const float pyy = b * b;
                const float pxy = a * b;
                #pragma unroll
                for (int j = 0; j < 4; ++j) {
                    const int t = k - j;
                    if (t >= 0 && t < 11) {
                        const float w = G[t];
                        s[0][j] = fmaf(w, a,   s[0][j]);
                        s[1][j] = fmaf(w, b,   s[1][j]);
                        s[2][j] = fmaf(w, pxx, s[2][j]);
                        s[3][j] = fmaf(w, pyy, s[3][j]);
                        s[4][j] = fmaf(w, pxy, s[4][j]);
                    }
                }
            }
        }
        #pragma unroll
        for (int q = 0; q < 5; ++q)
            #pragma unroll
            for (int j = 0; j < 4; ++j)
                sV[q][4 * g + j][cl] = s[q][j];
    }
}

__global__ __launch_bounds__(256, 6) void ssim_main(const float* __restrict__ img1,
                                                    const float* __restrict__ img2,
                                                    float* __restrict__ partial) {
    // 11-tap gaussian, sigma=1.5, normalized (double-precision precomputed)
    constexpr float G[11] = {0.00102838f, 0.00759876f, 0.03600077f, 0.10936069f,
                             0.21300554f, 0.26601172f, 0.21300554f, 0.10936069f,
                             0.03600077f, 0.00759876f, 0.00102838f};

    __shared__ __align__(16) float sV[5][TH][LC];   // 25600 B
    __shared__ float wsum[4];

    const int bid   = blockIdx.x;
    const int plane = bid >> 8;           // 256 tiles per plane
    const int rem   = bid & 255;
    const int tyi   = rem >> 3;           // 0..31
    const int txi   = rem & 7;            // 0..7
    const int r0    = tyi * TH;
    const int col0  = txi * TW;
    const float* __restrict__ p1 = img1 + (size_t)plane * (IMGH * IMGW);
    const float* __restrict__ p2 = img2 + (size_t)plane * (IMGH * IMGW);
    const int tid = threadIdx.x;

    // ---------- stage 1: vertical blur (coalesced loads) ----------
    // interior iff input rows [r0-5, r0+20] fully inside the image
    if (r0 >= 5 && r0 + 20 < IMGH)
        stage1<false>(p1, p2, r0, col0, tid, sV, G);
    else
        stage1<true >(p1, p2, r0, col0, tid, sV, G);
    __syncthreads();

    // ---------- stage 2: horizontal blur from LDS (float4-aligned) + ssim ----------
    float acc = 0.0f;
    {
        const int r = tid >> 4;           // 0..15
        const int t = tid & 15;           // 4-col group: output cols col0+4t..+3
        float q5[5][4];                   // [quantity][u]
        #pragma unroll
        for (int q = 0; q < 5; ++q) {
            float w[20];
            #pragma unroll
            for (int o = 0; o < 5; ++o) {
                const float4 v = *(const float4*)&sV[q][r][4 * t + 4 * o];
                w[4 * o + 0] = v.x; w[4 * o + 1] = v.y;
                w[4 * o + 2] = v.z; w[4 * o + 3] = v.w;
            }
            #pragma unroll
            for (int u = 0; u < 4; ++u) {
                float s = 0.0f;
                #pragma unroll
                for (int k = 0; k < 11; ++k)
                    s = fmaf(G[k], w[u + 3 + k], s);
                q5[q][u] = s;
            }
        }
        #pragma unroll
        for (int u = 0; u < 4; ++u)
            acc += ssim1(q5[0][u], q5[1][u], q5[2][u], q5[3][u], q5[4][u]);
    }

    // ---------- block reduction ----------
    #pragma unroll
    for (int off = 32; off > 0; off >>= 1)
        acc += __shfl_down(acc, off, 64);
    if ((tid & 63) == 0) wsum[tid >> 6] = acc;
    __syncthreads();
    if (tid == 0)
        partial[bid] = wsum[0] + wsum[1] + wsum[2] + wsum[3];
}

__global__ __launch_bounds__(256) void ssim_reduce(const float* __restrict__ partial,
                                                   float* __restrict__ out) {
    const int tid = threadIdx.x;
    double s = 0.0;
    for (int i = tid; i < NBLOCKS; i += 256)
        s += (double)partial[i];
    #pragma unroll
    for (int off = 32; off > 0; off >>= 1)
        s += __shfl_down(s, off, 64);
    __shared__ double wsd[4];
    if ((tid & 63) == 0) wsd[tid >> 6] = s;
    __syncthreads();
    if (tid == 0)
        out[0] = (float)((wsd[0] + wsd[1] + wsd[2] + wsd[3]) / NPIX);
}

extern "C" void kernel_launch(void* const* d_in, const int* in_sizes, int n_in,
                              void* d_out, int out_size, void* d_ws, size_t ws_size,
                              hipStream_t stream) {
    const float* img1 = (const float*)d_in[0];
    const float* img2 = (const float*)d_in[1];
    float* partial = (float*)d_ws;      // 12288 floats = 48 KB of scratch
    float* out = (float*)d_out;
    ssim_main<<<NBLOCKS, 256, 0, stream>>>(img1, img2, partial);
    ssim_reduce<<<1, 256, 0, stream>>>(partial, out);
}

// Round 4
// 80.658 us; speedup vs baseline: 2.5137x; 1.0686x over previous
//
#include <hip/hip_runtime.h>

// SSIM, fused separable 11x11 Gaussian blur + ssim map + mean.
// Images: (16,3,512,512) f32. Output: 1 f32 scalar.
// R4: R3 structure + (a) launch_bounds(256,4) to stop scratch spills
// (R3: VGPR=40, 65.6 MB scratch writes), (b) rcp+NR for the ssim divide,
// (c) single-wave block reduction reusing sV as scratch.

#define TW 64            // output cols per block
#define TH 16            // output rows per block
#define LC 80            // LDS cols: image cols [col0-8, col0+71]
#define IMGW 512
#define IMGH 512
#define NPL 48           // 16*3 planes
#define NTX (IMGW / TW)  // 8
#define NTY (IMGH / TH)  // 32
#define NBLOCKS (NPL * NTX * NTY)  // 12288
#define NPIX 12582912.0  // 16*3*512*512

__device__ __forceinline__ float ssim1(float mu1, float mu2, float exx, float eyy, float exy) {
    const float C1 = 1.0e-4f;   // 0.01^2
    const float C2 = 9.0e-4f;   // 0.03^2
    float mu1s = mu1 * mu1;
    float mu2s = mu2 * mu2;
    float mu12 = mu1 * mu2;
    float s1  = exx - mu1s;
    float s2  = eyy - mu2s;
    float s12 = exy - mu12;
    float num = (2.0f * mu12 + C1) * (2.0f * s12 + C2);
    float den = (mu1s + mu2s + C1) * (s1 + s2 + C2);
    // den > 0 always; v_rcp (1 ulp) + one Newton step -> ~f32-exact
    float r = __builtin_amdgcn_rcpf(den);
    r = r * fmaf(-den, r, 2.0f);
    return num * r;
}

// Stage 1: vertical blur of {x, y, x^2, y^2, xy} for one (column, 4-row group).
template<bool EDGE>
__device__ __forceinline__ void stage1(const float* __restrict__ p1,
                                       const float* __restrict__ p2,
                                       int r0, int col0, int tid,
                                       float (*sV)[TH][LC], const float* G) {
    #pragma unroll
    for (int it = 0; it < 2; ++it) {
        const int idx = tid + it * 256;
        if (it == 1 && idx >= LC * (TH / 4)) break;   // 320 tasks total
        const int cl = idx % LC;          // LDS col 0..79
        const int g  = idx / LC;          // 4-row group 0..3
        const int gc = col0 - 8 + cl;     // image col
        float s[5][4] = {};               // [quantity][row-in-group]
        if ((unsigned)gc < (unsigned)IMGW) {
            const float* __restrict__ c1 = p1 + gc;
            const float* __restrict__ c2 = p2 + gc;
            const int rbase = r0 + 4 * g - 5;
            #pragma unroll
            for (int k = 0; k < 14; ++k) {
                const int row = rbase + k;
                float a, b;
                if (EDGE) {
                    const bool ok = ((unsigned)row < (unsigned)IMGH);
                    const int rc = ok ? row : 0;
                    a = c1[(size_t)rc * IMGW];
                    b = c2[(size_t)rc * IMGW];
                    a = ok ? a : 0.0f;
                    b = ok ? b : 0.0f;
                } else {
                    a = c1[(size_t)row * IMGW];
                    b = c2[(size_t)row * IMGW];
                }
                const float pxx = a * a;
                const float pyy = b * b;
                const float pxy = a * b;
                #pragma unroll
                for (int j = 0; j < 4; ++j) {
                    const int t = k - j;
                    if (t >= 0 && t < 11) {
                        const float w = G[t];
                        s[0][j] = fmaf(w, a,   s[0][j]);
                        s[1][j] = fmaf(w, b,   s[1][j]);
                        s[2][j] = fmaf(w, pxx, s[2][j]);
                        s[3][j] = fmaf(w, pyy, s[3][j]);
                        s[4][j] = fmaf(w, pxy, s[4][j]);
                    }
                }
            }
        }
        #pragma unroll
        for (int q = 0; q < 5; ++q)
            #pragma unroll
            for (int j = 0; j < 4; ++j)
                sV[q][4 * g + j][cl] = s[q][j];
    }
}

__global__ __launch_bounds__(256, 4) void ssim_main(const float* __restrict__ img1,
                                                    const float* __restrict__ img2,
                                                    float* __restrict__ partial) {
    // 11-tap gaussian, sigma=1.5, normalized (double-precision precomputed)
    constexpr float G[11] = {0.00102838f, 0.00759876f, 0.03600077f, 0.10936069f,
                             0.21300554f, 0.26601172f, 0.21300554f, 0.10936069f,
                             0.03600077f, 0.00759876f, 0.00102838f};

    __shared__ __align__(16) float sV[5][TH][LC];   // 25600 B

    const int bid   = blockIdx.x;
    const int plane = bid >> 8;           // 256 tiles per plane
    const int rem   = bid & 255;
    const int tyi   = rem >> 3;           // 0..31
    const int txi   = rem & 7;            // 0..7
    const int r0    = tyi * TH;
    const int col0  = txi * TW;
    const float* __restrict__ p1 = img1 + (size_t)plane * (IMGH * IMGW);
    const float* __restrict__ p2 = img2 + (size_t)plane * (IMGH * IMGW);
    const int tid = threadIdx.x;

    // ---------- stage 1: vertical blur (coalesced loads) ----------
    // interior iff input rows [r0-5, r0+20] fully inside the image
    if (r0 >= 5 && r0 + 20 < IMGH)
        stage1<false>(p1, p2, r0, col0, tid, sV, G);
    else
        stage1<true >(p1, p2, r0, col0, tid, sV, G);
    __syncthreads();

    // ---------- stage 2: horizontal blur from LDS (float4-aligned) + ssim ----------
    float acc = 0.0f;
    {
        const int r = tid >> 4;           // 0..15
        const int t = tid & 15;           // 4-col group: output cols col0+4t..+3
        float q5[5][4];                   // [quantity][u]
        #pragma unroll
        for (int q = 0; q < 5; ++q) {
            float w[20];
            #pragma unroll
            for (int o = 0; o < 5; ++o) {
                const float4 v = *(const float4*)&sV[q][r][4 * t + 4 * o];
                w[4 * o + 0] = v.x; w[4 * o + 1] = v.y;
                w[4 * o + 2] = v.z; w[4 * o + 3] = v.w;
            }
            #pragma unroll
            for (int u = 0; u < 4; ++u) {
                float s = 0.0f;
                #pragma unroll
                for (int k = 0; k < 11; ++k)
                    s = fmaf(G[k], w[u + 3 + k], s);
                q5[q][u] = s;
            }
        }
        #pragma unroll
        for (int u = 0; u < 4; ++u)
            acc += ssim1(q5[0][u], q5[1][u], q5[2][u], q5[3][u], q5[4][u]);
    }

    // ---------- block reduction (single wave, reuse sV as scratch) ----------
    __syncthreads();                       // all sV reads done
    float* red = &sV[0][0][0];
    red[tid] = acc;
    __syncthreads();
    if (tid < 64) {
        const float4 v = ((const float4*)red)[tid];
        float s = (v.x + v.y) + (v.z + v.w);
        #pragma unroll
        for (int off = 32; off > 0; off >>= 1)
            s += __shfl_down(s, off, 64);
        if (tid == 0) partial[bid] = s;
    }
}

__global__ __launch_bounds__(256) void ssim_reduce(const float* __restrict__ partial,
                                                   float* __restrict__ out) {
    const int tid = threadIdx.x;
    double s = 0.0;
    for (int i = tid; i < NBLOCKS; i += 256)
        s += (double)partial[i];
    #pragma unroll
    for (int off = 32; off > 0; off >>= 1)
        s += __shfl_down(s, off, 64);
    __shared__ double wsd[4];
    if ((tid & 63) == 0) wsd[tid >> 6] = s;
    __syncthreads();
    if (tid == 0)
        out[0] = (float)((wsd[0] + wsd[1] + wsd[2] + wsd[3]) / NPIX);
}

extern "C" void kernel_launch(void* const* d_in, const int* in_sizes, int n_in,
                              void* d_out, int out_size, void* d_ws, size_t ws_size,
                              hipStream_t stream) {
    const float* img1 = (const float*)d_in[0];
    const float* img2 = (const float*)d_in[1];
    float* partial = (float*)d_ws;      // 12288 floats = 48 KB of scratch
    float* out = (float*)d_out;
    ssim_main<<<NBLOCKS, 256, 0, stream>>>(img1, img2, partial);
    ssim_reduce<<<1, 256, 0, stream>>>(partial, out);
}

// Round 5
// 70.961 us; speedup vs baseline: 2.8572x; 1.1366x over previous
//
#include <hip/hip_runtime.h>

// SSIM, fused separable 11x11 Gaussian blur + ssim map + mean.
// Images: (16,3,512,512) f32. Output: 1 f32 scalar.
// R5: pack {img1,img2} and {x^2,y^2} as float2 ext-vectors so the blur FMAs
// become v_pk_fma_f32 (2x f32/inst on CDNA4): 5 scalar chains -> 2 packed + 1
// scalar. Stage-2 lanes row-major + padded LDS strides for conflict-free b128.

#define TW 64            // output cols per block
#define TH 16            // output rows per block
#define LCM 74           // float2 cols in sMU/sSQ: image cols [col0-5, col0+68]
#define LCX 76           // padded float cols in sXY (74 used)
#define NTASK1 (LCM * (TH / 4))   // 296 stage-1 tasks
#define IMGW 512
#define IMGH 512
#define NPL 48           // 16*3 planes
#define NBLOCKS (NPL * (IMGW / TW) * (IMGH / TH))  // 12288
#define NPIX 12582912.0  // 16*3*512*512

typedef __attribute__((ext_vector_type(2))) float v2f;
typedef __attribute__((ext_vector_type(4))) float v4f;

// Stage 1: vertical blur of {(x,y) pair, (x^2,y^2) pair, xy} for one
// (column, 4-row group). Coalesced scalar column loads.
template<bool EDGE>
__device__ __forceinline__ void stage1(const float* __restrict__ p1,
                                       const float* __restrict__ p2,
                                       int r0, int col0, int tid,
                                       v2f (*sMU)[LCM], v2f (*sSQ)[LCM],
                                       float (*sXY)[LCX], const float* G) {
    #pragma unroll
    for (int it = 0; it < 2; ++it) {
        const int idx = tid + it * 256;
        if (it == 1 && idx >= NTASK1) break;
        const int cl = idx % LCM;         // LDS col 0..73
        const int g  = idx / LCM;         // 4-row group 0..3
        const int gc = col0 - 5 + cl;     // image col
        v2f   smu[4] = {};
        v2f   ssq[4] = {};
        float sxy[4] = {};
        if ((unsigned)gc < (unsigned)IMGW) {
            const float* __restrict__ c1 = p1 + gc;
            const float* __restrict__ c2 = p2 + gc;
            const int rbase = r0 + 4 * g - 5;
            #pragma unroll
            for (int k = 0; k < 14; ++k) {
                const int row = rbase + k;
                float a, b;
                if (EDGE) {
                    const bool ok = ((unsigned)row < (unsigned)IMGH);
                    const int rc = ok ? row : 0;
                    a = c1[(size_t)rc * IMGW];
                    b = c2[(size_t)rc * IMGW];
                    a = ok ? a : 0.0f;
                    b = ok ? b : 0.0f;
                } else {
                    a = c1[(size_t)row * IMGW];
                    b = c2[(size_t)row * IMGW];
                }
                const v2f ab = {a, b};
                const v2f sq = ab * ab;          // (a^2, b^2)  v_pk_mul_f32
                const float xy = a * b;
                #pragma unroll
                for (int j = 0; j < 4; ++j) {
                    const int t = k - j;
                    if (t >= 0 && t < 11) {
                        const v2f wk = {G[t], G[t]};
                        smu[j] = __builtin_elementwise_fma(wk, ab, smu[j]);
                        ssq[j] = __builtin_elementwise_fma(wk, sq, ssq[j]);
                        sxy[j] = fmaf(G[t], xy, sxy[j]);
                    }
                }
            }
        }
        #pragma unroll
        for (int j = 0; j < 4; ++j) {
            sMU[4 * g + j][cl] = smu[j];   // ds_write_b64
            sSQ[4 * g + j][cl] = ssq[j];
            sXY[4 * g + j][cl] = sxy[j];
        }
    }
}

__global__ __launch_bounds__(256, 4) void ssim_main(const float* __restrict__ img1,
                                                    const float* __restrict__ img2,
                                                    float* __restrict__ partial) {
    // 11-tap gaussian, sigma=1.5, normalized (double-precision precomputed)
    constexpr float G[11] = {0.00102838f, 0.00759876f, 0.03600077f, 0.10936069f,
                             0.21300554f, 0.26601172f, 0.21300554f, 0.10936069f,
                             0.03600077f, 0.00759876f, 0.00102838f};

    __shared__ __align__(16) v2f   sMU[TH][LCM];   // 9472 B
    __shared__ __align__(16) v2f   sSQ[TH][LCM];   // 9472 B
    __shared__ __align__(16) float sXY[TH][LCX];   // 4864 B

    const int bid   = blockIdx.x;
    const int plane = bid >> 8;           // 256 tiles per plane
    const int rem   = bid & 255;
    const int tyi   = rem >> 3;           // 0..31
    const int txi   = rem & 7;            // 0..7
    const int r0    = tyi * TH;
    const int col0  = txi * TW;
    const float* __restrict__ p1 = img1 + (size_t)plane * (IMGH * IMGW);
    const float* __restrict__ p2 = img2 + (size_t)plane * (IMGH * IMGW);
    const int tid = threadIdx.x;

    // ---------- stage 1: vertical blur (coalesced loads, packed FMA) ----------
    if (r0 >= 5 && r0 + 20 < IMGH)
        stage1<false>(p1, p2, r0, col0, tid, sMU, sSQ, sXY, G);
    else
        stage1<true >(p1, p2, r0, col0, tid, sMU, sSQ, sXY, G);
    __syncthreads();

    // ---------- stage 2: horizontal blur from LDS + ssim ----------
    // lanes row-major: consecutive lanes -> consecutive rows -> b128 batches
    // span all 32 banks (strides 74*2 and 76 chosen for this).
    float acc = 0.0f;
    {
        const int r = tid & 15;           // row 0..15
        const int t = tid >> 4;           // 4-col output group 0..15
        v2f amu[4] = {};
        v2f asq[4] = {};
        float axy[4] = {};
        {   // mu pair: window cols 4t .. 4t+13 (float2 elems)
            v2f w[14];
            #pragma unroll
            for (int o = 0; o < 7; ++o) {
                const v4f v = *(const v4f*)&sMU[r][4 * t + 2 * o];
                w[2 * o]     = (v2f){v.x, v.y};
                w[2 * o + 1] = (v2f){v.z, v.w};
            }
            #pragma unroll
            for (int u = 0; u < 4; ++u)
                #pragma unroll
                for (int k = 0; k < 11; ++k) {
                    const v2f wk = {G[k], G[k]};
                    amu[u] = __builtin_elementwise_fma(wk, w[u + k], amu[u]);
                }
        }
        {   // (x^2,y^2) pair
            v2f w[14];
            #pragma unroll
            for (int o = 0; o < 7; ++o) {
                const v4f v = *(const v4f*)&sSQ[r][4 * t + 2 * o];
                w[2 * o]     = (v2f){v.x, v.y};
                w[2 * o + 1] = (v2f){v.z, v.w};
            }
            #pragma unroll
            for (int u = 0; u < 4; ++u)
                #pragma unroll
                for (int k = 0; k < 11; ++k) {
                    const v2f wk = {G[k], G[k]};
                    asq[u] = __builtin_elementwise_fma(wk, w[u + k], asq[u]);
                }
        }
        {   // xy scalar
            float w[16];
            #pragma unroll
            for (int o = 0; o < 4; ++o) {
                const v4f v = *(const v4f*)&sXY[r][4 * t + 4 * o];
                w[4 * o]     = v.x;
                w[4 * o + 1] = v.y;
                w[4 * o + 2] = v.z;
                w[4 * o + 3] = v.w;
            }
            #pragma unroll
            for (int u = 0; u < 4; ++u)
                #pragma unroll
                for (int k = 0; k < 11; ++k)
                    axy[u] = fmaf(G[k], w[u + k], axy[u]);
        }
        const float C1 = 1.0e-4f;   // 0.01^2
        const float C2 = 9.0e-4f;   // 0.03^2
        #pragma unroll
        for (int u = 0; u < 4; ++u) {
            const v2f mu   = amu[u];          // (mu1, mu2)
            const v2f musq = mu * mu;         // (mu1^2, mu2^2)
            const float mu12 = mu.x * mu.y;
            const v2f sig  = asq[u] - musq;   // (sigma1^2, sigma2^2)
            const float s12 = axy[u] - mu12;
            const float num = fmaf(2.0f, mu12, C1) * fmaf(2.0f, s12, C2);
            const float den = (musq.x + musq.y + C1) * (sig.x + sig.y + C2);
            float rd = __builtin_amdgcn_rcpf(den);   // den > 0 always
            rd = rd * fmaf(-den, rd, 2.0f);          // Newton step
            acc += num * rd;
        }
    }

    // ---------- block reduction (single wave, reuse LDS as scratch) ----------
    __syncthreads();                       // all LDS reads done
    float* red = (float*)&sMU[0][0];
    red[tid] = acc;
    __syncthreads();
    if (tid < 64) {
        const v4f v = ((const v4f*)red)[tid];
        float s = (v.x + v.y) + (v.z + v.w);
        #pragma unroll
        for (int off = 32; off > 0; off >>= 1)
            s += __shfl_down(s, off, 64);
        if (tid == 0) partial[bid] = s;
    }
}

__global__ __launch_bounds__(256) void ssim_reduce(const float* __restrict__ partial,
                                                   float* __restrict__ out) {
    const int tid = threadIdx.x;
    double s = 0.0;
    for (int i = tid; i < NBLOCKS; i += 256)
        s += (double)partial[i];
    #pragma unroll
    for (int off = 32; off > 0; off >>= 1)
        s += __shfl_down(s, off, 64);
    __shared__ double wsd[4];
    if ((tid & 63) == 0) wsd[tid >> 6] = s;
    __syncthreads();
    if (tid == 0)
        out[0] = (float)((wsd[0] + wsd[1] + wsd[2] + wsd[3]) / NPIX);
}

extern "C" void kernel_launch(void* const* d_in, const int* in_sizes, int n_in,
                              void* d_out, int out_size, void* d_ws, size_t ws_size,
                              hipStream_t stream) {
    const float* img1 = (const float*)d_in[0];
    const float* img2 = (const float*)d_in[1];
    float* partial = (float*)d_ws;      // 12288 floats = 48 KB of scratch
    float* out = (float*)d_out;
    ssim_main<<<NBLOCKS, 256, 0, stream>>>(img1, img2, partial);
    ssim_reduce<<<1, 256, 0, stream>>>(partial, out);
}

// Round 6
// 61.805 us; speedup vs baseline: 3.2804x; 1.1481x over previous
//
#include <hip/hip_runtime.h>

// SSIM, fused separable 11x11 Gaussian blur + ssim map + mean.
// Images: (16,3,512,512) f32. Output: 1 f32 scalar.
// R6: TW=128 x TH=8 tile (halo waste 15.6%->7.8%, division-free stage-1
// mapping, 22.1 KB LDS -> 7 blocks/CU ceiling), launch_bounds(256,6),
// fused mu+sq stage-2 loops, 1024-thread reduce kernel.

#define TW 128           // output cols per block
#define TH 8             // output rows per block
#define LCM 138          // v2f cols in sMU/sSQ: image cols [col0-5, col0+132]
#define LCX 140          // padded f32 cols in sXY (138 used; 140 for b128 row align)
#define NTASK1 (LCM * (TH / 4))   // 276 stage-1 tasks (2 row-groups)
#define IMGW 512
#define IMGH 512
#define NPL 48           // 16*3 planes
#define NBLOCKS (NPL * (IMGW / TW) * (IMGH / TH))  // 12288
#define NPIX 12582912.0  // 16*3*512*512
#define REDT 1024        // reduce-kernel threads

typedef __attribute__((ext_vector_type(2))) float v2f;
typedef __attribute__((ext_vector_type(4))) float v4f;

// Stage 1: vertical blur of {(x,y) pair, (x^2,y^2) pair, xy} for one
// (column, 4-row group). Coalesced scalar column loads.
template<bool EDGE>
__device__ __forceinline__ void stage1(const float* __restrict__ p1,
                                       const float* __restrict__ p2,
                                       int r0, int col0, int tid,
                                       v2f (*sMU)[LCM], v2f (*sSQ)[LCM],
                                       float (*sXY)[LCX], const float* G) {
    #pragma unroll
    for (int it = 0; it < 2; ++it) {
        if (it == 1 && tid >= NTASK1 - 256) break;   // 20 leftover tasks
        const int idx = tid + it * 256;
        const int g  = (idx >= LCM) ? 1 : 0;         // 4-row group 0..1
        const int cl = idx - g * LCM;                // LDS col 0..137
        const int gc = col0 - 5 + cl;                // image col
        v2f   smu[4] = {};
        v2f   ssq[4] = {};
        float sxy[4] = {};
        if ((unsigned)gc < (unsigned)IMGW) {
            const float* __restrict__ c1 = p1 + gc;
            const float* __restrict__ c2 = p2 + gc;
            const int rbase = r0 + 4 * g - 5;
            #pragma unroll
            for (int k = 0; k < 14; ++k) {
                const int row = rbase + k;
                float a, b;
                if (EDGE) {
                    const bool ok = ((unsigned)row < (unsigned)IMGH);
                    const int rc = ok ? row : 0;
                    a = c1[(size_t)rc * IMGW];
                    b = c2[(size_t)rc * IMGW];
                    a = ok ? a : 0.0f;
                    b = ok ? b : 0.0f;
                } else {
                    a = c1[(size_t)row * IMGW];
                    b = c2[(size_t)row * IMGW];
                }
                const v2f ab = {a, b};
                const v2f sq = ab * ab;          // v_pk_mul_f32
                const float xy = a * b;
                #pragma unroll
                for (int j = 0; j < 4; ++j) {
                    const int t = k - j;
                    if (t >= 0 && t < 11) {
                        const v2f wk = {G[t], G[t]};
                        smu[j] = __builtin_elementwise_fma(wk, ab, smu[j]);
                        ssq[j] = __builtin_elementwise_fma(wk, sq, ssq[j]);
                        sxy[j] = fmaf(G[t], xy, sxy[j]);
                    }
                }
            }
        }
        #pragma unroll
        for (int j = 0; j < 4; ++j) {
            sMU[4 * g + j][cl] = smu[j];   // ds_write_b64
            sSQ[4 * g + j][cl] = ssq[j];
            sXY[4 * g + j][cl] = sxy[j];
        }
    }
}

__global__ __launch_bounds__(256, 6) void ssim_main(const float* __restrict__ img1,
                                                    const float* __restrict__ img2,
                                                    float* __restrict__ partial) {
    // 11-tap gaussian, sigma=1.5, normalized (double-precision precomputed)
    constexpr float G[11] = {0.00102838f, 0.00759876f, 0.03600077f, 0.10936069f,
                             0.21300554f, 0.26601172f, 0.21300554f, 0.10936069f,
                             0.03600077f, 0.00759876f, 0.00102838f};

    __shared__ __align__(16) v2f   sMU[TH][LCM];   // 8832 B
    __shared__ __align__(16) v2f   sSQ[TH][LCM];   // 8832 B
    __shared__ __align__(16) float sXY[TH][LCX];   // 4480 B

    const int bid   = blockIdx.x;
    const int plane = bid >> 8;           // 256 tiles per plane
    const int rem   = bid & 255;
    const int tyi   = rem >> 2;           // 0..63
    const int txi   = rem & 3;            // 0..3
    const int r0    = tyi * TH;
    const int col0  = txi * TW;
    const float* __restrict__ p1 = img1 + (size_t)plane * (IMGH * IMGW);
    const float* __restrict__ p2 = img2 + (size_t)plane * (IMGH * IMGW);
    const int tid = threadIdx.x;

    // ---------- stage 1: vertical blur (coalesced loads, packed FMA) ----------
    // interior iff input rows [r0-5, r0+12] fully inside the image
    if (tyi >= 1 && tyi <= 62)
        stage1<false>(p1, p2, r0, col0, tid, sMU, sSQ, sXY, G);
    else
        stage1<true >(p1, p2, r0, col0, tid, sMU, sSQ, sXY, G);
    __syncthreads();

    // ---------- stage 2: horizontal blur from LDS + ssim ----------
    float acc = 0.0f;
    {
        const int r = tid & 7;            // row 0..7
        const int t = tid >> 3;           // 4-col output group 0..31
        v2f amu[4] = {};
        v2f asq[4] = {};
        float axy[4] = {};
        {   // mu + sq pairs: window v2f elems 4t .. 4t+13
            v2f wm[14], ws[14];
            #pragma unroll
            for (int o = 0; o < 7; ++o) {
                const v4f vm = *(const v4f*)&sMU[r][4 * t + 2 * o];
                const v4f vs = *(const v4f*)&sSQ[r][4 * t + 2 * o];
                wm[2 * o]     = (v2f){vm.x, vm.y};
                wm[2 * o + 1] = (v2f){vm.z, vm.w};
                ws[2 * o]     = (v2f){vs.x, vs.y};
                ws[2 * o + 1] = (v2f){vs.z, vs.w};
            }
            #pragma unroll
            for (int u = 0; u < 4; ++u)
                #pragma unroll
                for (int k = 0; k < 11; ++k) {
                    const v2f wk = {G[k], G[k]};
                    amu[u] = __builtin_elementwise_fma(wk, wm[u + k], amu[u]);
                    asq[u] = __builtin_elementwise_fma(wk, ws[u + k], asq[u]);
                }
        }
        {   // xy scalar
            float w[16];
            #pragma unroll
            for (int o = 0; o < 4; ++o) {
                const v4f v = *(const v4f*)&sXY[r][4 * t + 4 * o];
                w[4 * o]     = v.x;
                w[4 * o + 1] = v.y;
                w[4 * o + 2] = v.z;
                w[4 * o + 3] = v.w;
            }
            #pragma unroll
            for (int u = 0; u < 4; ++u)
                #pragma unroll
                for (int k = 0; k < 11; ++k)
                    axy[u] = fmaf(G[k], w[u + k], axy[u]);
        }
        const float C1 = 1.0e-4f;   // 0.01^2
        const float C2 = 9.0e-4f;   // 0.03^2
        #pragma unroll
        for (int u = 0; u < 4; ++u) {
            const v2f mu   = amu[u];          // (mu1, mu2)
            const v2f musq = mu * mu;         // (mu1^2, mu2^2)
            const float mu12 = mu.x * mu.y;
            const v2f sig  = asq[u] - musq;   // (sigma1^2, sigma2^2)
            const float s12 = axy[u] - mu12;
            const float num = fmaf(2.0f, mu12, C1) * fmaf(2.0f, s12, C2);
            const float den = (musq.x + musq.y + C1) * (sig.x + sig.y + C2);
            float rd = __builtin_amdgcn_rcpf(den);   // den > 0 always
            rd = rd * fmaf(-den, rd, 2.0f);          // Newton step
            acc += num * rd;
        }
    }

    // ---------- block reduction (single wave, reuse LDS as scratch) ----------
    __syncthreads();                       // all LDS reads done
    float* red = (float*)&sMU[0][0];
    red[tid] = acc;
    __syncthreads();
    if (tid < 64) {
        const v4f v = ((const v4f*)red)[tid];
        float s = (v.x + v.y) + (v.z + v.w);
        #pragma unroll
        for (int off = 32; off > 0; off >>= 1)
            s += __shfl_down(s, off, 64);
        if (tid == 0) partial[bid] = s;
    }
}

__global__ __launch_bounds__(REDT) void ssim_reduce(const float* __restrict__ partial,
                                                    float* __restrict__ out) {
    const int tid = threadIdx.x;
    double s = 0.0;
    #pragma unroll
    for (int i = tid; i < NBLOCKS; i += REDT)
        s += (double)partial[i];
    #pragma unroll
    for (int off = 32; off > 0; off >>= 1)
        s += __shfl_down(s, off, 64);
    __shared__ double wsd[REDT / 64];
    if ((tid & 63) == 0) wsd[tid >> 6] = s;
    __syncthreads();
    if (tid == 0) {
        double t = 0.0;
        #pragma unroll
        for (int i = 0; i < REDT / 64; ++i) t += wsd[i];
        out[0] = (float)(t / NPIX);
    }
}

extern "C" void kernel_launch(void* const* d_in, const int* in_sizes, int n_in,
                              void* d_out, int out_size, void* d_ws, size_t ws_size,
                              hipStream_t stream) {
    const float* img1 = (const float*)d_in[0];
    const float* img2 = (const float*)d_in[1];
    float* partial = (float*)d_ws;      // 12288 floats = 48 KB of scratch
    float* out = (float*)d_out;
    ssim_main<<<NBLOCKS, 256, 0, stream>>>(img1, img2, partial);
    ssim_reduce<<<1, REDT, 0, stream>>>(partial, out);
}

// Round 8
// 46.364 us; speedup vs baseline: 4.3730x; 1.3331x over previous
//
#include <hip/hip_runtime.h>

// SSIM via MFMA: both separable 11-tap Gaussian passes are matmuls by a
// constant banded matrix (f16 inputs, f32 accumulate).
// V-pass computed transposed (D'[vcol][row]) so each lane's V output IS the
// A-fragment of the H-pass: zero LDS, zero barriers, waves independent.
// k-slot mapping kappa(g,j) = {4g+j, 16+4g+(j-4)} used consistently for A and
// B of both passes (R7 confirmed layout correct).
// R8 fix: the f16-cast Gaussian taps sum to s = 1048748/2^20 = 1.000164032,
// so every blurred quantity carries scale t = s^2; this biased sigma12 by
// t(1-t)*mu1mu2 and the mean SSIM by -1.0e-3 (measured 9.77e-4). Correct all
// five H-pass results by 1/t = 0.99967202 before the SSIM math.

typedef _Float16 f16;
typedef __attribute__((ext_vector_type(4))) _Float16 f16x4;
typedef __attribute__((ext_vector_type(8))) _Float16 f16x8;
typedef __attribute__((ext_vector_type(4))) float f32x4;

#define IMGW 512
#define IMGH 512
#define NPL 48           // 16*3 planes
#define NBX 8            // col tiles (512/64)
#define NBY 8            // row bands (512/64)
#define NBLOCKS (NPL * NBX * NBY)   // 3072
#define NPIX 12582912.0
#define REDT 1024

// inverse of total f16-weight scale: s = sum of f16(G) = 1048748/2^20,
// t = s^2, 1/t = 0.99967201677
#define INV_T 0.99967202f

// 11-tap gaussian, sigma=1.5, normalized (double-precision precomputed)
__device__ const float G_dev[11] = {0.00102838f, 0.00759876f, 0.03600077f,
                                    0.10936069f, 0.21300554f, 0.26601172f,
                                    0.21300554f, 0.10936069f, 0.03600077f,
                                    0.00759876f, 0.00102838f};

__global__ __launch_bounds__(256) void ssim_main(const float* __restrict__ img1,
                                                 const float* __restrict__ img2,
                                                 float* __restrict__ partial) {
    const int tid  = threadIdx.x;
    const int lane = tid & 63;
    const int wv   = tid >> 6;         // wave 0..3 (stacked vertically)
    const int l15  = lane & 15;
    const int lg   = lane >> 4;        // 0..3

    const int bid   = blockIdx.x;
    const int plane = bid >> 6;        // 64 tiles per plane
    const int rem   = bid & 63;
    const int by    = rem >> 3;
    const int bx    = rem & 7;
    const int r0    = by * 64 + wv * 16;   // wave's first output row
    const int c0    = bx * 64;             // first output col

    const float* __restrict__ p1 = img1 + (size_t)plane * (IMGH * IMGW);
    const float* __restrict__ p2 = img2 + (size_t)plane * (IMGH * IMGW);

    // logical k-slot mapping (same for A and B of both passes)
    int kap[8];
    #pragma unroll
    for (int j = 0; j < 8; ++j)
        kap[j] = (j < 4) ? (4 * lg + j) : (16 + 4 * lg + (j - 4));

    // constant band fragment: B[k][n] = G[kappa(k) - n], n = l15
    f16x8 bband;
    #pragma unroll
    for (int j = 0; j < 8; ++j) {
        const int t = kap[j] - l15;
        const float w = (t >= 0 && t < 11) ? G_dev[t] : 0.0f;
        bband[j] = (f16)w;
    }

    const f32x4 zero4 = {0.0f, 0.0f, 0.0f, 0.0f};

    // V-pass: per chunk t, A[i=vcol][k=row-slot] from global, transposed mfma.
    // Lane ends up with V at (row r0+l15, vcols 16t+4lg+{0..3}) as f16x4.
    f16x4 hv[5][5];    // [chunk][quantity: x,y,xx,yy,xy]
    #pragma unroll
    for (int t = 0; t < 5; ++t) {
        const int c   = c0 - 5 + 16 * t + l15;   // img col for this lane
        const bool cok = ((unsigned)c < (unsigned)IMGW);
        const int cc  = cok ? c : 0;
        float xv[8], yv[8];
        #pragma unroll
        for (int j = 0; j < 8; ++j) {
            const int rho = r0 - 5 + kap[j];
            const bool ok = cok && ((unsigned)rho < (unsigned)IMGH) && (kap[j] < 26);
            const int rc  = ((unsigned)rho < (unsigned)IMGH) ? rho : 0;
            const size_t off = (size_t)rc * IMGW + cc;
            const float a = p1[off];
            const float b = p2[off];
            xv[j] = ok ? a : 0.0f;
            yv[j] = ok ? b : 0.0f;
        }
        f16x8 fx, fy;
        #pragma unroll
        for (int j = 0; j < 8; ++j) {
            fx[j] = (f16)xv[j];
            fy[j] = (f16)yv[j];
        }
        const f16x8 fxx = fx * fx;   // v_pk_mul_f16
        const f16x8 fyy = fy * fy;
        const f16x8 fxy = fx * fy;

        const f32x4 dx  = __builtin_amdgcn_mfma_f32_16x16x32_f16(fx,  bband, zero4, 0, 0, 0);
        const f32x4 dy  = __builtin_amdgcn_mfma_f32_16x16x32_f16(fy,  bband, zero4, 0, 0, 0);
        const f32x4 dxx = __builtin_amdgcn_mfma_f32_16x16x32_f16(fxx, bband, zero4, 0, 0, 0);
        const f32x4 dyy = __builtin_amdgcn_mfma_f32_16x16x32_f16(fyy, bband, zero4, 0, 0, 0);
        const f32x4 dxy = __builtin_amdgcn_mfma_f32_16x16x32_f16(fxy, bband, zero4, 0, 0, 0);

        hv[t][0] = (f16x4){(f16)dx[0],  (f16)dx[1],  (f16)dx[2],  (f16)dx[3]};
        hv[t][1] = (f16x4){(f16)dy[0],  (f16)dy[1],  (f16)dy[2],  (f16)dy[3]};
        hv[t][2] = (f16x4){(f16)dxx[0], (f16)dxx[1], (f16)dxx[2], (f16)dxx[3]};
        hv[t][3] = (f16x4){(f16)dyy[0], (f16)dyy[1], (f16)dyy[2], (f16)dyy[3]};
        hv[t][4] = (f16x4){(f16)dxy[0], (f16)dxy[1], (f16)dxy[2], (f16)dxy[3]};
    }

    // H-pass + ssim. A_h for out-chunk m = concat(hv[m][q], hv[m+1][q]).
    float acc = 0.0f;
    const float C1 = 1.0e-4f;   // 0.01^2
    const float C2 = 9.0e-4f;   // 0.03^2
    #pragma unroll
    for (int m = 0; m < 4; ++m) {
        f32x4 h[5];
        #pragma unroll
        for (int q = 0; q < 5; ++q) {
            const f16x8 a = __builtin_shufflevector(hv[m][q], hv[m + 1][q],
                                                    0, 1, 2, 3, 4, 5, 6, 7);
            h[q] = __builtin_amdgcn_mfma_f32_16x16x32_f16(a, bband, zero4, 0, 0, 0);
            h[q] *= INV_T;   // remove f16-weight-sum scale (s^2 per quantity)
        }
        #pragma unroll
        for (int r = 0; r < 4; ++r) {
            const float mu1 = h[0][r], mu2 = h[1][r];
            const float exx = h[2][r], eyy = h[3][r], exy = h[4][r];
            const float mu1s = mu1 * mu1;
            const float mu2s = mu2 * mu2;
            const float mu12 = mu1 * mu2;
            const float s1  = exx - mu1s;
            const float s2  = eyy - mu2s;
            const float s12 = exy - mu12;
            const float num = fmaf(2.0f, mu12, C1) * fmaf(2.0f, s12, C2);
            const float den = (mu1s + mu2s + C1) * (s1 + s2 + C2);
            float rd = __builtin_amdgcn_rcpf(den);   // den > 0 always
            rd = rd * fmaf(-den, rd, 2.0f);          // Newton step
            acc = fmaf(num, rd, acc);
        }
    }

    // block reduction
    #pragma unroll
    for (int off = 32; off > 0; off >>= 1)
        acc += __shfl_down(acc, off, 64);
    __shared__ float wsum[4];
    if (lane == 0) wsum[wv] = acc;
    __syncthreads();
    if (tid == 0)
        partial[bid] = (wsum[0] + wsum[1]) + (wsum[2] + wsum[3]);
}

__global__ __launch_bounds__(REDT) void ssim_reduce(const float* __restrict__ partial,
                                                    float* __restrict__ out) {
    const int tid = threadIdx.x;
    double s = 0.0;
    for (int i = tid; i < NBLOCKS; i += REDT)
        s += (double)partial[i];
    #pragma unroll
    for (int off = 32; off > 0; off >>= 1)
        s += __shfl_down(s, off, 64);
    __shared__ double wsd[REDT / 64];
    if ((tid & 63) == 0) wsd[tid >> 6] = s;
    __syncthreads();
    if (tid == 0) {
        double t = 0.0;
        #pragma unroll
        for (int i = 0; i < REDT / 64; ++i) t += wsd[i];
        out[0] = (float)(t / NPIX);
    }
}

extern "C" void kernel_launch(void* const* d_in, const int* in_sizes, int n_in,
                              void* d_out, int out_size, void* d_ws, size_t ws_size,
                              hipStream_t stream) {
    const float* img1 = (const float*)d_in[0];
    const float* img2 = (const float*)d_in[1];
    float* partial = (float*)d_ws;      // 3072 floats
    float* out = (float*)d_out;
    ssim_main<<<NBLOCKS, 256, 0, stream>>>(img1, img2, partial);
    ssim_reduce<<<1, REDT, 0, stream>>>(partial, out);
}